// Round 10
// baseline (309.484 us; speedup 1.0000x reference)
//
#include <hip/hip_runtime.h>
#include <hip/hip_bf16.h>
#include <math.h>

#define BB 16
#define NN 2048

typedef short bf16x8 __attribute__((ext_vector_type(8)));
typedef float f32x4 __attribute__((ext_vector_type(4)));
typedef unsigned long long u64;

#define MFMA(a, b, c) __builtin_amdgcn_mfma_f32_16x16x32_bf16(a, b, c, 0, 0, 0)

static __device__ __forceinline__ short f2bf(float f) {
  union { float f; unsigned u; } v; v.f = f;
  unsigned r = v.u + 0x7fffu + ((v.u >> 16) & 1u);
  return (short)(r >> 16);
}
static __device__ __forceinline__ short f2bf_hw(float f) {
  unsigned u;
  asm("v_cvt_pk_bf16_f32 %0, %1, %1" : "=v"(u) : "v"(f));
  return (short)u;
}
static __device__ __forceinline__ unsigned f2bf2(float lo, float hi) {
  unsigned u;
  asm("v_cvt_pk_bf16_f32 %0, %1, %2" : "=v"(u) : "v"(lo), "v"(hi));
  return u;
}

// ---------------- K1: h = relu(bn(conv1d(x))) ; xx = ||h||^2 ----------------
__global__ __launch_bounds__(256) void k_h(const float* __restrict__ x,
                                           const float* __restrict__ lw,
                                           const float* __restrict__ ls,
                                           const float* __restrict__ lb,
                                           float* __restrict__ h,
                                           float* __restrict__ xx) {
  int p = blockIdx.x * blockDim.x + threadIdx.x;
  if (p >= BB * NN) return;
  int b = p >> 11;
  int n = p & (NN - 1);
  const float* xb = x + (size_t)b * 3 * NN + n;
  float x0 = xb[0], x1 = xb[NN], x2 = xb[2 * NN];
  float hv[8];
  float ss = 0.f;
#pragma unroll
  for (int o = 0; o < 8; ++o) {
    float v = x0 * lw[o * 3 + 0] + x1 * lw[o * 3 + 1] + x2 * lw[o * 3 + 2];
    v = fmaxf(v * ls[o] + lb[o], 0.f);
    hv[o] = v;
    ss += v * v;  // same order as k_knn inner product -> self-dist exactly 0
  }
  float4* hp = (float4*)(h + (size_t)p * 8);
  hp[0] = make_float4(hv[0], hv[1], hv[2], hv[3]);
  hp[1] = make_float4(hv[4], hv[5], hv[6], hv[7]);
  xx[p] = ss;
}

// ---------------- K2: kNN top-16 (unchanged from r9) ----------------
__global__ __launch_bounds__(512, 4) void k_knn(const float* __restrict__ h,
                                                const float* __restrict__ xx,
                                                int* __restrict__ knn_idx) {
  __shared__ __align__(16) unsigned char smem[52224];
  float4* sh4 = (float4*)smem;
  float* sxx = (float*)(smem + 16384);
  unsigned* thr = (unsigned*)(smem + 18432);
  u64* stkb = (u64*)(smem + 18688);

  int tid = threadIdx.x;
  int lane = tid & 63;
  int w = tid >> 6;
  int blk = blockIdx.x;
  int b = blk >> 5;
  int qloc = ((blk & 31) << 6) + lane;
  int p = (b << 11) + qloc;
  const float* hb = h + ((size_t)b << 11) * 8;
  const float* xxb = xx + ((size_t)b << 11);

  const float4* qp = (const float4*)(hb + (size_t)qloc * 8);
  float4 q0 = qp[0], q1 = qp[1];
  float xq = xxb[qloc];

  if (tid < 64) thr[tid] = 0x007FFFFFu;
  __syncthreads();

  u64* stkrow = stkb + tid * 8;
  u64 a[16];
#pragma unroll
  for (int i = 0; i < 16; ++i) a[i] = 0ULL;
  int cnt = 0;

  auto inner8 = [&](int s) -> float {
    float4 a0 = sh4[(w * 64 + s) * 2 + 0];
    float4 a1 = sh4[(w * 64 + s) * 2 + 1];
    return q0.x * a0.x + q0.y * a0.y + q0.z * a0.z + q0.w * a0.w +
           q1.x * a1.x + q1.y * a1.y + q1.z * a1.z + q1.w * a1.w;
  };
  auto mkkey = [&](float d, int mg) -> u64 {
    unsigned uu = __float_as_uint(d);
    unsigned key = ((int)uu >= 0) ? (uu | 0x80000000u) : ~uu;
    return ((u64)key << 32) | (unsigned)(NN - 1 - mg);
  };

  auto flush = [&]() {
    u64 c[8];
#pragma unroll
    for (int j = 0; j < 8; ++j) {
      u64 v = stkrow[j];
      c[j] = (j < cnt) ? v : 0ULL;
    }
    cnt = 0;
#pragma unroll
    for (int k = 2; k <= 8; k <<= 1)
#pragma unroll
      for (int j = k >> 1; j > 0; j >>= 1)
#pragma unroll
        for (int i = 0; i < 8; ++i) {
          int l = i ^ j;
          if (l > i) {
            bool up = ((i & k) == 0);
            u64 xi = c[i], xl = c[l];
            bool sw = up ? (xi > xl) : (xi < xl);
            if (sw) { c[i] = xl; c[l] = xi; }
          }
        }
    u64 m[16];
#pragma unroll
    for (int i = 0; i < 16; ++i) {
      u64 bi = (i < 8) ? c[7 - i] : 0ULL;
      m[i] = (a[i] > bi) ? a[i] : bi;
    }
#pragma unroll
    for (int j = 8; j > 0; j >>= 1)
#pragma unroll
      for (int i = 0; i < 16; ++i) {
        int l = i ^ j;
        if (l > i && m[i] > m[l]) { u64 t = m[i]; m[i] = m[l]; m[l] = t; }
      }
#pragma unroll
    for (int i = 0; i < 16; ++i) a[i] = m[i];
  };

  int sbase = w * 256;
  float4 r0, r1;
  float rx;
  {
    const float* cp = hb + (size_t)(sbase + lane) * 8;
    r0 = *(const float4*)cp;
    r1 = *(const float4*)(cp + 4);
    rx = xxb[sbase + lane];
  }
  for (int c2 = 0; c2 < 4; ++c2) {
    sh4[(w * 64 + lane) * 2 + 0] = r0;
    sh4[(w * 64 + lane) * 2 + 1] = r1;
    sxx[w * 64 + lane] = rx;
    if (c2 < 3) {
      const float* cp = hb + (size_t)(sbase + (c2 + 1) * 64 + lane) * 8;
      r0 = *(const float4*)cp;
      r1 = *(const float4*)(cp + 4);
      rx = xxb[sbase + (c2 + 1) * 64 + lane];
    }
    int mg0 = sbase + c2 * 64;
    int sstart = 0;
    if (c2 == 0) {
      u64 cc[16];
#pragma unroll
      for (int j = 0; j < 16; ++j) cc[j] = mkkey(2.f * inner8(j) - xq - sxx[w * 64 + j], mg0 + j);
#pragma unroll
      for (int k = 2; k <= 16; k <<= 1)
#pragma unroll
        for (int j = k >> 1; j > 0; j >>= 1)
#pragma unroll
          for (int i = 0; i < 16; ++i) {
            int l = i ^ j;
            if (l > i) {
              bool up = ((i & k) == 0);
              u64 xi = cc[i], xl = cc[l];
              bool sw = up ? (xi > xl) : (xi < xl);
              if (sw) { cc[i] = xl; cc[l] = xi; }
            }
          }
#pragma unroll
      for (int i = 0; i < 16; ++i) a[i] = cc[i];
      atomicMax(&thr[lane], (unsigned)(a[0] >> 32));
      sstart = 16;
    }
    for (int s16 = sstart; s16 < 64; s16 += 16) {
      unsigned t32 = thr[lane];
      unsigned tu = (t32 & 0x80000000u) ? (t32 & 0x7fffffffu) : ~t32;
      float thrF = __uint_as_float(tu);
#pragma unroll
      for (int s4 = 0; s4 < 16; s4 += 4) {
        int s = s16 + s4;
        float4 xm4 = *(const float4*)&sxx[w * 64 + s];
#pragma unroll
        for (int u = 0; u < 4; ++u) {
          float xm = (u == 0) ? xm4.x : (u == 1) ? xm4.y : (u == 2) ? xm4.z : xm4.w;
          float d = 2.f * inner8(s + u) - xq - xm;
          if (d >= thrF) { stkrow[cnt] = mkkey(d, mg0 + s + u); cnt++; }
        }
        if (__any(cnt >= 5)) {
          flush();
          atomicMax(&thr[lane], (unsigned)(a[0] >> 32));
          unsigned t2 = thr[lane];
          unsigned tu2 = (t2 & 0x80000000u) ? (t2 & 0x7fffffffu) : ~t2;
          thrF = __uint_as_float(tu2);
        }
      }
    }
  }
  if (__any(cnt > 0)) flush();

  u64* M1 = (u64*)smem;
  u64* M2 = (u64*)(smem + 34816);
  u64* M3 = (u64*)smem;

  auto mergeLds = [&](const u64* src) {
    u64 m[16];
#pragma unroll
    for (int i = 0; i < 16; ++i) {
      u64 bi = src[15 - i];
      m[i] = (a[i] > bi) ? a[i] : bi;
    }
#pragma unroll
    for (int j = 8; j > 0; j >>= 1)
#pragma unroll
      for (int i = 0; i < 16; ++i) {
        int l = i ^ j;
        if (l > i && m[i] > m[l]) { u64 t = m[i]; m[i] = m[l]; m[l] = t; }
      }
#pragma unroll
    for (int i = 0; i < 16; ++i) a[i] = m[i];
  };

  __syncthreads();
  if (w >= 4) {
#pragma unroll
    for (int i = 0; i < 16; ++i) M1[((w - 4) * 64 + lane) * 17 + i] = a[i];
  }
  __syncthreads();
  if (w < 4) mergeLds(&M1[(w * 64 + lane) * 17]);
  __syncthreads();
  if (w == 2 || w == 3) {
#pragma unroll
    for (int i = 0; i < 16; ++i) M2[((w - 2) * 64 + lane) * 17 + i] = a[i];
  }
  __syncthreads();
  if (w < 2) mergeLds(&M2[(w * 64 + lane) * 17]);
  __syncthreads();
  if (w == 1) {
#pragma unroll
    for (int i = 0; i < 16; ++i) M3[lane * 17 + i] = a[i];
  }
  __syncthreads();
  if (w == 0) {
    mergeLds(&M3[lane * 17]);
    int ids[16];
#pragma unroll
    for (int r = 0; r < 16; ++r)
      ids[r] = (NN - 1) - (int)(unsigned)(a[15 - r] & 0xFFFFFFFFULL);
    int4* op = (int4*)(knn_idx + (size_t)p * 16);
    op[0] = make_int4(ids[0], ids[1], ids[2], ids[3]);
    op[1] = make_int4(ids[4], ids[5], ids[6], ids[7]);
    op[2] = make_int4(ids[8], ids[9], ids[10], ids[11]);
    op[3] = make_int4(ids[12], ids[13], ids[14], ids[15]);
  }
}

// ---------------- unified weight pack ----------------
__global__ __launch_bounds__(64) void k_packall(
    const float* __restrict__ w1, const float* __restrict__ w3,
    const float* __restrict__ w2, const float* __restrict__ w4,
    const float* __restrict__ a1_att, const float* __restrict__ a2_att,
    const float* __restrict__ a1_w, const float* __restrict__ a2_w,
    const float* __restrict__ wf,
    short* __restrict__ w1f, short* __restrict__ w3f,
    short* __restrict__ w2f, short* __restrict__ w4f,
    short* __restrict__ wa1f, short* __restrict__ wa2f,
    short* __restrict__ wp1f, short* __restrict__ wp2f,
    short* __restrict__ wff) {
  int bb = blockIdx.x;
  const float* src;
  short* dst;
  int O, C, base;
  if (bb < 4)        { src = w1;     dst = w1f;  O = 64;  C = 16;  base = 0; }
  else if (bb < 8)   { src = w3;     dst = w3f;  O = 64;  C = 16;  base = 4; }
  else if (bb < 24)  { src = w2;     dst = w2f;  O = 128; C = 64;  base = 8; }
  else if (bb < 40)  { src = w4;     dst = w4f;  O = 128; C = 64;  base = 24; }
  else if (bb < 72)  { src = a1_att; dst = wa1f; O = 128; C = 128; base = 40; }
  else if (bb < 104) { src = a2_att; dst = wa2f; O = 128; C = 128; base = 72; }
  else if (bb < 168) { src = a1_w;   dst = wp1f; O = 256; C = 128; base = 104; }
  else if (bb < 232) { src = a2_w;   dst = wp2f; O = 256; C = 128; base = 168; }
  else               { src = wf;     dst = wff;  O = 512; C = 512; base = 232; }
  int blk = bb - base;
  int NCT = O >> 4;
  int ct = blk % NCT;
  int kt = blk / NCT;
  int l = threadIdx.x;
  int col = ct * 16 + (l & 15);
  bf16x8 v;
#pragma unroll
  for (int i = 0; i < 8; ++i) {
    int k = kt * 32 + ((l >> 4) << 3) + i;
    v[i] = (k < C) ? f2bf(src[(size_t)col * C + k]) : (short)0;
  }
  ((bf16x8*)dst)[(size_t)blk * 64 + l] = v;
}

// ---------------- K3: edge->conv1->conv2->score->pool. Swapped-operand MFMA: ----------------
// D = MFMA(w_frag, x_frag) gives col=lane&15=row, reg=channel -> each thread holds 4
// CONSECUTIVE channels of one row => b64 LDS writes (conflict-free), float4 scale/bias.
__global__ __launch_bounds__(512, 4) void k_branch_all(
    const float* __restrict__ h, const int* __restrict__ knn_idx,
    const short* __restrict__ w1f, const float* __restrict__ s1, const float* __restrict__ b1,
    const short* __restrict__ w2f, const float* __restrict__ s2, const float* __restrict__ b2,
    const short* __restrict__ wa1f,
    const short* __restrict__ w3f, const float* __restrict__ s3, const float* __restrict__ b3,
    const short* __restrict__ w4f, const float* __restrict__ s4, const float* __restrict__ b4,
    const short* __restrict__ wa2f,
    short* __restrict__ fout) {
  __shared__ short e_s[128][40];    // stride 80B
  __shared__ short g1_s[128][72];   // stride 144B
  __shared__ short g2_s[128][136];  // stride 272B

  int br = blockIdx.y;
  const short* W1 = br ? w3f : w1f;
  const float* S1 = br ? s3 : s1;
  const float* B1 = br ? b3 : b1;
  const short* W2 = br ? w4f : w2f;
  const float* S2 = br ? s4 : s2;
  const float* B2 = br ? b4 : b2;
  const short* WA = br ? wa2f : wa1f;
  int KR = br ? 12 : 16;
  int FOFF = br ? 256 : 0;

  int tid = threadIdx.x;
  int lane = tid & 63;
  int w = tid >> 6;
  int lr = lane & 15;
  int lg = lane >> 4;
  int pbase = blockIdx.x * 8;
  const float* hb = h + ((size_t)(pbase & ~(NN - 1))) * 8;

  // Phase A: edge features; all 512 threads, quarter-row each
  {
    int t = tid >> 2, q4 = tid & 3;     // t = row (point*16+nbr), q4 = channel quarter
    int pt = t >> 4, j = t & 15;
    int p = pbase + pt;
    bool real = (j < KR);
    unsigned dd = 0, cc2 = 0;
    if (real) {
      int id = knn_idx[(size_t)p * 16 + j];
      const float* cp = h + (size_t)p * 8 + q4 * 2;
      const float* np_ = hb + (size_t)id * 8 + q4 * 2;
      float2 cv = *(const float2*)cp;
      float2 nv = *(const float2*)np_;
      dd = f2bf2(nv.x - cv.x, nv.y - cv.y);
      cc2 = f2bf2(cv.x, cv.y);
    }
    *(unsigned*)&e_s[t][q4 * 2] = dd;
    *(unsigned*)&e_s[t][8 + q4 * 2] = cc2;
    *(uint2*)&e_s[t][16 + q4 * 4] = make_uint2(0, 0);  // K-pad
  }
  __syncthreads();

  // Phase B: conv1 16->64 (transposed out). wave: ct=w&3, row-half w>>2.
  {
    int ct = w & 3;
    int rhalf = w >> 2;
    bf16x8 wfrag = ((const bf16x8*)W1)[ct * 64 + lane];
    float4 scl4 = *(const float4*)&S1[ct * 16 + lg * 4];
    float4 bia4 = *(const float4*)&B1[ct * 16 + lg * 4];
#pragma unroll
    for (int rt = 0; rt < 4; ++rt) {
      int rr = rhalf * 4 + rt;
      bf16x8 ef = *(const bf16x8*)&e_s[rr * 16 + lr][lg * 8];
      f32x4 acc = {0.f, 0.f, 0.f, 0.f};
      acc = MFMA(wfrag, ef, acc);
      float v0 = fmaxf(acc[0] * scl4.x + bia4.x, 0.f);
      float v1 = fmaxf(acc[1] * scl4.y + bia4.y, 0.f);
      float v2 = fmaxf(acc[2] * scl4.z + bia4.z, 0.f);
      float v3 = fmaxf(acc[3] * scl4.w + bia4.w, 0.f);
      *(uint2*)&g1_s[rr * 16 + lr][ct * 16 + lg * 4] =
          make_uint2(f2bf2(v0, v1), f2bf2(v2, v3));
    }
  }
  __syncthreads();

  // Phase C: conv2 64->128 (transposed out); fp32 copies kept for pooling
  float g2r[8][4];
  {
    int ct = w;
    bf16x8 wf0 = ((const bf16x8*)W2)[(0 * 8 + ct) * 64 + lane];
    bf16x8 wf1 = ((const bf16x8*)W2)[(1 * 8 + ct) * 64 + lane];
    float4 scl4 = *(const float4*)&S2[ct * 16 + lg * 4];
    float4 bia4 = *(const float4*)&B2[ct * 16 + lg * 4];
#pragma unroll
    for (int rt = 0; rt < 8; ++rt) {
      bf16x8 b0 = *(const bf16x8*)&g1_s[rt * 16 + lr][lg * 8];
      bf16x8 b1 = *(const bf16x8*)&g1_s[rt * 16 + lr][32 + lg * 8];
      f32x4 acc = {0.f, 0.f, 0.f, 0.f};
      acc = MFMA(wf0, b0, acc);
      acc = MFMA(wf1, b1, acc);
      float v0 = fmaxf(acc[0] * scl4.x + bia4.x, 0.f);
      float v1 = fmaxf(acc[1] * scl4.y + bia4.y, 0.f);
      float v2 = fmaxf(acc[2] * scl4.z + bia4.z, 0.f);
      float v3 = fmaxf(acc[3] * scl4.w + bia4.w, 0.f);
      g2r[rt][0] = v0; g2r[rt][1] = v1; g2r[rt][2] = v2; g2r[rt][3] = v3;
      *(uint2*)&g2_s[rt * 16 + lr][ct * 16 + lg * 4] =
          make_uint2(f2bf2(v0, v1), f2bf2(v2, v3));
    }
  }
  __syncthreads();

  // Phase D: score (transposed: acc[q]=score[row=lr][ch=ct*16+lg*4+q]) aligns with g2r;
  // sigmoid-gate, mask rows lr>=KR, 4-step shfl tree over lr, pooled -> fbuf cols [FOFF,+128)
  {
    int ct = w;
    bf16x8 wa[4];
#pragma unroll
    for (int kt = 0; kt < 4; ++kt) wa[kt] = ((const bf16x8*)WA)[(kt * 8 + ct) * 64 + lane];
#pragma unroll
    for (int rt = 0; rt < 8; ++rt) {
      f32x4 acc = {0.f, 0.f, 0.f, 0.f};
#pragma unroll
      for (int kt = 0; kt < 4; ++kt) {
        bf16x8 g2f = *(const bf16x8*)&g2_s[rt * 16 + lr][kt * 32 + lg * 8];
        acc = MFMA(wa[kt], g2f, acc);
      }
      float vq[4];
#pragma unroll
      for (int q = 0; q < 4; ++q) {
        float sg = __builtin_amdgcn_rcpf(1.f + __expf(-acc[q]));
        float t = g2r[rt][q] * sg;
        vq[q] = (lr < KR) ? t : 0.f;
      }
#pragma unroll
      for (int q = 0; q < 4; ++q) {
        vq[q] += __shfl_xor(vq[q], 1);
        vq[q] += __shfl_xor(vq[q], 2);
        vq[q] += __shfl_xor(vq[q], 4);
        vq[q] += __shfl_xor(vq[q], 8);
      }
      if ((lane & 15) == 0) {
        *(uint2*)(fout + (size_t)(pbase + rt) * 512 + FOFF + ct * 16 + lg * 4) =
            make_uint2(f2bf2(vq[0], vq[1]), f2bf2(vq[2], vq[3]));
      }
    }
  }
}

// ---------------- K3b: att conv 128->256 per branch, IN-PLACE on fbuf ----------------
__global__ __launch_bounds__(256, 4) void k_att(
    short* __restrict__ fb,
    const short* __restrict__ wp1f, const float* __restrict__ a1s, const float* __restrict__ a1b,
    const short* __restrict__ wp2f, const float* __restrict__ a2s, const float* __restrict__ a2b) {
  __shared__ short ptile[64][136];
  int br = blockIdx.y;
  const short* WP = br ? wp2f : wp1f;
  const float* SP = br ? a2s : a1s;
  const float* BP = br ? a2b : a1b;
  int FOFF = br ? 256 : 0;

  int tid = threadIdx.x;
  int lane = tid & 63;
  int w = tid >> 6;
  int lr = lane & 15;
  int lg = lane >> 4;
  int p0 = blockIdx.x * 64;

#pragma unroll
  for (int i = 0; i < 4; ++i) {
    int f = i * 256 + tid;
    int row = f >> 4, seg = f & 15;
    *(float4*)&ptile[row][seg * 8] =
        *(const float4*)(fb + (size_t)(p0 + row) * 512 + FOFF + seg * 8);
  }
  __syncthreads();

  bf16x8 af[4][4];
#pragma unroll
  for (int rt = 0; rt < 4; ++rt)
#pragma unroll
    for (int kt = 0; kt < 4; ++kt)
      af[rt][kt] = *(const bf16x8*)&ptile[rt * 16 + lr][kt * 32 + lg * 8];

#pragma unroll
  for (int cc = 0; cc < 4; ++cc) {
    int ct = w * 4 + cc;
    int o = ct * 16 + lr;
    bf16x8 bfr[4];
#pragma unroll
    for (int kt = 0; kt < 4; ++kt) bfr[kt] = ((const bf16x8*)WP)[(kt * 16 + ct) * 64 + lane];
    float scl = SP[o], bia = BP[o];
#pragma unroll
    for (int rt = 0; rt < 4; ++rt) {
      f32x4 acc = {0.f, 0.f, 0.f, 0.f};
#pragma unroll
      for (int kt = 0; kt < 4; ++kt) acc = MFMA(af[rt][kt], bfr[kt], acc);
#pragma unroll
      for (int q = 0; q < 4; ++q) {
        float v = fmaxf(acc[q] * scl + bia, 0.f);
        fb[(size_t)(p0 + rt * 16 + lg * 4 + q) * 512 + FOFF + o] = f2bf_hw(v);
      }
    }
  }
}

// ---------------- K4: out = relu(bn(f @ wf^T)) computed transposed ----------------
__global__ __launch_bounds__(256, 4) void k_final(
    const short* __restrict__ fbuf, const short* __restrict__ wff,
    const float* __restrict__ sf, const float* __restrict__ bfv,
    float* __restrict__ out) {
  __shared__ short b_s[256][72];
  int tid = threadIdx.x;
  int lane = tid & 63;
  int w = tid >> 6;
  int lr = lane & 15;
  int lg = lane >> 4;
  int ob = blockIdx.x;
  int p0 = blockIdx.y * 256;
  int rtg = ob * 4 + w;

  f32x4 acc[16];
#pragma unroll
  for (int ct = 0; ct < 16; ++ct) acc[ct] = (f32x4){0.f, 0.f, 0.f, 0.f};

  for (int kc = 0; kc < 512; kc += 64) {
    __syncthreads();
#pragma unroll
    for (int c = 0; c < 8; ++c) {
      int idx = c * 256 + tid;
      int row = idx >> 3, seg = idx & 7;
      *(float4*)&b_s[row][seg * 8] =
          *(const float4*)(fbuf + ((size_t)(p0 + row) * 512 + kc + seg * 8));
    }
    __syncthreads();
    int kt = kc >> 5;
    bf16x8 a0 = ((const bf16x8*)wff)[((size_t)(kt + 0) * 32 + rtg) * 64 + lane];
    bf16x8 a1 = ((const bf16x8*)wff)[((size_t)(kt + 1) * 32 + rtg) * 64 + lane];
#pragma unroll
    for (int ct = 0; ct < 16; ++ct) {
      bf16x8 bb0 = *(const bf16x8*)&b_s[ct * 16 + lr][lg * 8];
      bf16x8 bb1 = *(const bf16x8*)&b_s[ct * 16 + lr][32 + lg * 8];
      acc[ct] = MFMA(a0, bb0, acc[ct]);
      acc[ct] = MFMA(a1, bb1, acc[ct]);
    }
  }

  int b = p0 >> 11;
  int nb = p0 & (NN - 1);
#pragma unroll
  for (int q = 0; q < 4; ++q) {
    int o = rtg * 16 + lg * 4 + q;
    float scl = sf[o], bia = bfv[o];
#pragma unroll
    for (int ct = 0; ct < 16; ++ct) {
      int n = nb + ct * 16 + lr;
      float v = fmaxf(acc[ct][q] * scl + bia, 0.f);
      out[((size_t)b * 512 + o) * NN + n] = v;
    }
  }
}

extern "C" void kernel_launch(void* const* d_in, const int* in_sizes, int n_in,
                              void* d_out, int out_size, void* d_ws, size_t ws_size,
                              hipStream_t stream) {
  const float* x      = (const float*)d_in[0];
  const float* lw     = (const float*)d_in[1];
  const float* ls     = (const float*)d_in[2];
  const float* lb     = (const float*)d_in[3];
  const float* w1     = (const float*)d_in[4];
  const float* s1     = (const float*)d_in[5];
  const float* b1     = (const float*)d_in[6];
  const float* w2     = (const float*)d_in[7];
  const float* s2     = (const float*)d_in[8];
  const float* b2     = (const float*)d_in[9];
  const float* w3     = (const float*)d_in[10];
  const float* s3     = (const float*)d_in[11];
  const float* b3     = (const float*)d_in[12];
  const float* w4     = (const float*)d_in[13];
  const float* s4     = (const float*)d_in[14];
  const float* b4     = (const float*)d_in[15];
  const float* a1_att = (const float*)d_in[16];
  const float* a1_w   = (const float*)d_in[17];
  const float* a1_s   = (const float*)d_in[18];
  const float* a1_b   = (const float*)d_in[19];
  const float* a2_att = (const float*)d_in[20];
  const float* a2_w   = (const float*)d_in[21];
  const float* a2_s   = (const float*)d_in[22];
  const float* a2_b   = (const float*)d_in[23];
  const float* wf     = (const float*)d_in[24];
  const float* sf     = (const float*)d_in[25];
  const float* bf     = (const float*)d_in[26];
  float* out = (float*)d_out;

  char* ws = (char*)d_ws;
  float* h   = (float*)ws;                          ws += (size_t)BB * NN * 8 * 4;
  float* xx  = (float*)ws;                          ws += (size_t)BB * NN * 4;
  int* knn_idx = (int*)ws;                          ws += (size_t)BB * NN * 16 * 4;
  short* fbuf  = (short*)ws;                        ws += (size_t)BB * NN * 512 * 2;
  short* w1f   = (short*)ws;                        ws += 1 * 4 * 64 * 8 * 2;
  short* w3f   = (short*)ws;                        ws += 1 * 4 * 64 * 8 * 2;
  short* w2f   = (short*)ws;                        ws += 2 * 8 * 64 * 8 * 2;
  short* w4f   = (short*)ws;                        ws += 2 * 8 * 64 * 8 * 2;
  short* wa1f  = (short*)ws;                        ws += 4 * 8 * 64 * 8 * 2;
  short* wa2f  = (short*)ws;                        ws += 4 * 8 * 64 * 8 * 2;
  short* wp1f  = (short*)ws;                        ws += 4 * 16 * 64 * 8 * 2;
  short* wp2f  = (short*)ws;                        ws += 4 * 16 * 64 * 8 * 2;
  short* wff   = (short*)ws;                        ws += 16 * 32 * 64 * 8 * 2;

  k_packall<<<dim3(744), dim3(64), 0, stream>>>(
      w1, w3, w2, w4, a1_att, a2_att, a1_w, a2_w, wf,
      w1f, w3f, w2f, w4f, wa1f, wa2f, wp1f, wp2f, wff);

  k_h<<<dim3((BB * NN + 255) / 256), dim3(256), 0, stream>>>(x, lw, ls, lb, h, xx);
  k_knn<<<dim3(512), dim3(512), 0, stream>>>(h, xx, knn_idx);
  k_branch_all<<<dim3(BB * NN / 8, 2), dim3(512), 0, stream>>>(
      h, knn_idx,
      w1f, s1, b1, w2f, s2, b2, wa1f,
      w3f, s3, b3, w4f, s4, b4, wa2f, fbuf);
  k_att<<<dim3(BB * NN / 64, 2), dim3(256), 0, stream>>>(
      fbuf, wp1f, a1_s, a1_b, wp2f, a2_s, a2_b);
  k_final<<<dim3(8, 128), dim3(256), 0, stream>>>(fbuf, wff, sf, bf, out);
}

// Round 11
// 247.198 us; speedup vs baseline: 1.2520x; 1.2520x over previous
//
#include <hip/hip_runtime.h>
#include <hip/hip_bf16.h>
#include <math.h>

#define BB 16
#define NN 2048

typedef short bf16x8 __attribute__((ext_vector_type(8)));
typedef float f32x4 __attribute__((ext_vector_type(4)));
typedef unsigned long long u64;

#define MFMA(a, b, c) __builtin_amdgcn_mfma_f32_16x16x32_bf16(a, b, c, 0, 0, 0)

static __device__ __forceinline__ short f2bf(float f) {
  union { float f; unsigned u; } v; v.f = f;
  unsigned r = v.u + 0x7fffu + ((v.u >> 16) & 1u);
  return (short)(r >> 16);
}
static __device__ __forceinline__ short f2bf_hw(float f) {
  unsigned u;
  asm("v_cvt_pk_bf16_f32 %0, %1, %1" : "=v"(u) : "v"(f));
  return (short)u;
}
static __device__ __forceinline__ unsigned f2bf2(float lo, float hi) {
  unsigned u;
  asm("v_cvt_pk_bf16_f32 %0, %1, %2" : "=v"(u) : "v"(lo), "v"(hi));
  return u;
}

// ---------------- K1: h = relu(bn(conv1d(x))) ; xx = ||h||^2 ----------------
__global__ __launch_bounds__(256) void k_h(const float* __restrict__ x,
                                           const float* __restrict__ lw,
                                           const float* __restrict__ ls,
                                           const float* __restrict__ lb,
                                           float* __restrict__ h,
                                           float* __restrict__ xx) {
  int p = blockIdx.x * blockDim.x + threadIdx.x;
  if (p >= BB * NN) return;
  int b = p >> 11;
  int n = p & (NN - 1);
  const float* xb = x + (size_t)b * 3 * NN + n;
  float x0 = xb[0], x1 = xb[NN], x2 = xb[2 * NN];
  float hv[8];
  float ss = 0.f;
#pragma unroll
  for (int o = 0; o < 8; ++o) {
    float v = x0 * lw[o * 3 + 0] + x1 * lw[o * 3 + 1] + x2 * lw[o * 3 + 2];
    v = fmaxf(v * ls[o] + lb[o], 0.f);
    hv[o] = v;
    ss += v * v;  // same order as k_knn inner product -> self-dist exactly 0
  }
  float4* hp = (float4*)(h + (size_t)p * 8);
  hp[0] = make_float4(hv[0], hv[1], hv[2], hv[3]);
  hp[1] = make_float4(hv[4], hv[5], hv[6], hv[7]);
  xx[p] = ss;
}

// ---------------- K2: kNN top-16 (r8/r9 version, proven) ----------------
__global__ __launch_bounds__(512, 4) void k_knn(const float* __restrict__ h,
                                                const float* __restrict__ xx,
                                                int* __restrict__ knn_idx) {
  __shared__ __align__(16) unsigned char smem[52224];
  float4* sh4 = (float4*)smem;
  float* sxx = (float*)(smem + 16384);
  unsigned* thr = (unsigned*)(smem + 18432);
  u64* stkb = (u64*)(smem + 18688);

  int tid = threadIdx.x;
  int lane = tid & 63;
  int w = tid >> 6;
  int blk = blockIdx.x;
  int b = blk >> 5;
  int qloc = ((blk & 31) << 6) + lane;
  int p = (b << 11) + qloc;
  const float* hb = h + ((size_t)b << 11) * 8;
  const float* xxb = xx + ((size_t)b << 11);

  const float4* qp = (const float4*)(hb + (size_t)qloc * 8);
  float4 q0 = qp[0], q1 = qp[1];
  float xq = xxb[qloc];

  if (tid < 64) thr[tid] = 0x007FFFFFu;
  __syncthreads();

  u64* stkrow = stkb + tid * 8;
  u64 a[16];
#pragma unroll
  for (int i = 0; i < 16; ++i) a[i] = 0ULL;
  int cnt = 0;

  auto inner8 = [&](int s) -> float {
    float4 a0 = sh4[(w * 64 + s) * 2 + 0];
    float4 a1 = sh4[(w * 64 + s) * 2 + 1];
    return q0.x * a0.x + q0.y * a0.y + q0.z * a0.z + q0.w * a0.w +
           q1.x * a1.x + q1.y * a1.y + q1.z * a1.z + q1.w * a1.w;
  };
  auto mkkey = [&](float d, int mg) -> u64 {
    unsigned uu = __float_as_uint(d);
    unsigned key = ((int)uu >= 0) ? (uu | 0x80000000u) : ~uu;
    return ((u64)key << 32) | (unsigned)(NN - 1 - mg);
  };

  auto flush = [&]() {
    u64 c[8];
#pragma unroll
    for (int j = 0; j < 8; ++j) {
      u64 v = stkrow[j];
      c[j] = (j < cnt) ? v : 0ULL;
    }
    cnt = 0;
#pragma unroll
    for (int k = 2; k <= 8; k <<= 1)
#pragma unroll
      for (int j = k >> 1; j > 0; j >>= 1)
#pragma unroll
        for (int i = 0; i < 8; ++i) {
          int l = i ^ j;
          if (l > i) {
            bool up = ((i & k) == 0);
            u64 xi = c[i], xl = c[l];
            bool sw = up ? (xi > xl) : (xi < xl);
            if (sw) { c[i] = xl; c[l] = xi; }
          }
        }
    u64 m[16];
#pragma unroll
    for (int i = 0; i < 16; ++i) {
      u64 bi = (i < 8) ? c[7 - i] : 0ULL;
      m[i] = (a[i] > bi) ? a[i] : bi;
    }
#pragma unroll
    for (int j = 8; j > 0; j >>= 1)
#pragma unroll
      for (int i = 0; i < 16; ++i) {
        int l = i ^ j;
        if (l > i && m[i] > m[l]) { u64 t = m[i]; m[i] = m[l]; m[l] = t; }
      }
#pragma unroll
    for (int i = 0; i < 16; ++i) a[i] = m[i];
  };

  int sbase = w * 256;
  float4 r0, r1;
  float rx;
  {
    const float* cp = hb + (size_t)(sbase + lane) * 8;
    r0 = *(const float4*)cp;
    r1 = *(const float4*)(cp + 4);
    rx = xxb[sbase + lane];
  }
  for (int c2 = 0; c2 < 4; ++c2) {
    sh4[(w * 64 + lane) * 2 + 0] = r0;
    sh4[(w * 64 + lane) * 2 + 1] = r1;
    sxx[w * 64 + lane] = rx;
    if (c2 < 3) {
      const float* cp = hb + (size_t)(sbase + (c2 + 1) * 64 + lane) * 8;
      r0 = *(const float4*)cp;
      r1 = *(const float4*)(cp + 4);
      rx = xxb[sbase + (c2 + 1) * 64 + lane];
    }
    int mg0 = sbase + c2 * 64;
    int sstart = 0;
    if (c2 == 0) {
      u64 cc[16];
#pragma unroll
      for (int j = 0; j < 16; ++j) cc[j] = mkkey(2.f * inner8(j) - xq - sxx[w * 64 + j], mg0 + j);
#pragma unroll
      for (int k = 2; k <= 16; k <<= 1)
#pragma unroll
        for (int j = k >> 1; j > 0; j >>= 1)
#pragma unroll
          for (int i = 0; i < 16; ++i) {
            int l = i ^ j;
            if (l > i) {
              bool up = ((i & k) == 0);
              u64 xi = cc[i], xl = cc[l];
              bool sw = up ? (xi > xl) : (xi < xl);
              if (sw) { cc[i] = xl; cc[l] = xi; }
            }
          }
#pragma unroll
      for (int i = 0; i < 16; ++i) a[i] = cc[i];
      atomicMax(&thr[lane], (unsigned)(a[0] >> 32));
      sstart = 16;
    }
    for (int s16 = sstart; s16 < 64; s16 += 16) {
      unsigned t32 = thr[lane];
      unsigned tu = (t32 & 0x80000000u) ? (t32 & 0x7fffffffu) : ~t32;
      float thrF = __uint_as_float(tu);
#pragma unroll
      for (int s4 = 0; s4 < 16; s4 += 4) {
        int s = s16 + s4;
        float4 xm4 = *(const float4*)&sxx[w * 64 + s];
#pragma unroll
        for (int u = 0; u < 4; ++u) {
          float xm = (u == 0) ? xm4.x : (u == 1) ? xm4.y : (u == 2) ? xm4.z : xm4.w;
          float d = 2.f * inner8(s + u) - xq - xm;
          if (d >= thrF) { stkrow[cnt] = mkkey(d, mg0 + s + u); cnt++; }
        }
        if (__any(cnt >= 5)) {
          flush();
          atomicMax(&thr[lane], (unsigned)(a[0] >> 32));
          unsigned t2 = thr[lane];
          unsigned tu2 = (t2 & 0x80000000u) ? (t2 & 0x7fffffffu) : ~t2;
          thrF = __uint_as_float(tu2);
        }
      }
    }
  }
  if (__any(cnt > 0)) flush();

  u64* M1 = (u64*)smem;
  u64* M2 = (u64*)(smem + 34816);
  u64* M3 = (u64*)smem;

  auto mergeLds = [&](const u64* src) {
    u64 m[16];
#pragma unroll
    for (int i = 0; i < 16; ++i) {
      u64 bi = src[15 - i];
      m[i] = (a[i] > bi) ? a[i] : bi;
    }
#pragma unroll
    for (int j = 8; j > 0; j >>= 1)
#pragma unroll
      for (int i = 0; i < 16; ++i) {
        int l = i ^ j;
        if (l > i && m[i] > m[l]) { u64 t = m[i]; m[i] = m[l]; m[l] = t; }
      }
#pragma unroll
    for (int i = 0; i < 16; ++i) a[i] = m[i];
  };

  __syncthreads();
  if (w >= 4) {
#pragma unroll
    for (int i = 0; i < 16; ++i) M1[((w - 4) * 64 + lane) * 17 + i] = a[i];
  }
  __syncthreads();
  if (w < 4) mergeLds(&M1[(w * 64 + lane) * 17]);
  __syncthreads();
  if (w == 2 || w == 3) {
#pragma unroll
    for (int i = 0; i < 16; ++i) M2[((w - 2) * 64 + lane) * 17 + i] = a[i];
  }
  __syncthreads();
  if (w < 2) mergeLds(&M2[(w * 64 + lane) * 17]);
  __syncthreads();
  if (w == 1) {
#pragma unroll
    for (int i = 0; i < 16; ++i) M3[lane * 17 + i] = a[i];
  }
  __syncthreads();
  if (w == 0) {
    mergeLds(&M3[lane * 17]);
    int ids[16];
#pragma unroll
    for (int r = 0; r < 16; ++r)
      ids[r] = (NN - 1) - (int)(unsigned)(a[15 - r] & 0xFFFFFFFFULL);
    int4* op = (int4*)(knn_idx + (size_t)p * 16);
    op[0] = make_int4(ids[0], ids[1], ids[2], ids[3]);
    op[1] = make_int4(ids[4], ids[5], ids[6], ids[7]);
    op[2] = make_int4(ids[8], ids[9], ids[10], ids[11]);
    op[3] = make_int4(ids[12], ids[13], ids[14], ids[15]);
  }
}

// ---------------- unified weight pack ----------------
__global__ __launch_bounds__(64) void k_packall(
    const float* __restrict__ w1, const float* __restrict__ w3,
    const float* __restrict__ w2, const float* __restrict__ w4,
    const float* __restrict__ a1_att, const float* __restrict__ a2_att,
    const float* __restrict__ a1_w, const float* __restrict__ a2_w,
    const float* __restrict__ wf,
    short* __restrict__ w1f, short* __restrict__ w3f,
    short* __restrict__ w2f, short* __restrict__ w4f,
    short* __restrict__ wa1f, short* __restrict__ wa2f,
    short* __restrict__ wp1f, short* __restrict__ wp2f,
    short* __restrict__ wff) {
  int bb = blockIdx.x;
  const float* src;
  short* dst;
  int O, C, base;
  if (bb < 4)        { src = w1;     dst = w1f;  O = 64;  C = 16;  base = 0; }
  else if (bb < 8)   { src = w3;     dst = w3f;  O = 64;  C = 16;  base = 4; }
  else if (bb < 24)  { src = w2;     dst = w2f;  O = 128; C = 64;  base = 8; }
  else if (bb < 40)  { src = w4;     dst = w4f;  O = 128; C = 64;  base = 24; }
  else if (bb < 72)  { src = a1_att; dst = wa1f; O = 128; C = 128; base = 40; }
  else if (bb < 104) { src = a2_att; dst = wa2f; O = 128; C = 128; base = 72; }
  else if (bb < 168) { src = a1_w;   dst = wp1f; O = 256; C = 128; base = 104; }
  else if (bb < 232) { src = a2_w;   dst = wp2f; O = 256; C = 128; base = 168; }
  else               { src = wf;     dst = wff;  O = 512; C = 512; base = 232; }
  int blk = bb - base;
  int NCT = O >> 4;
  int ct = blk % NCT;
  int kt = blk / NCT;
  int l = threadIdx.x;
  int col = ct * 16 + (l & 15);
  bf16x8 v;
#pragma unroll
  for (int i = 0; i < 8; ++i) {
    int k = kt * 32 + ((l >> 4) << 3) + i;
    v[i] = (k < C) ? f2bf(src[(size_t)col * C + k]) : (short)0;
  }
  ((bf16x8*)dst)[(size_t)blk * 64 + l] = v;
}

// ---------------- K3: edge->conv1->conv2->att-score->pool (r9 body) ----------------
// LDS overlay: e_s (dead after phase B) shares the g2_s region (born in phase C).
// 52 KB total -> 3 blocks/CU (was 63.5 KB -> 2). VGPR 52 << 85 cap of (512,6): no spill.
__global__ __launch_bounds__(512, 6) void k_branch_all(
    const float* __restrict__ h, const int* __restrict__ knn_idx,
    const short* __restrict__ w1f, const float* __restrict__ s1, const float* __restrict__ b1,
    const short* __restrict__ w2f, const float* __restrict__ s2, const float* __restrict__ b2,
    const short* __restrict__ wa1f,
    const short* __restrict__ w3f, const float* __restrict__ s3, const float* __restrict__ b3,
    const short* __restrict__ w4f, const float* __restrict__ s4, const float* __restrict__ b4,
    const short* __restrict__ wa2f,
    short* __restrict__ fout) {
  __shared__ __align__(16) unsigned char smem[53248];
  short (*e_s)[40]  = (short(*)[40])smem;              // [128][40], phases A-B only
  short (*g2_s)[136] = (short(*)[136])smem;            // [128][136], phases C-D (overlays e_s)
  short (*g1_s)[72] = (short(*)[72])(smem + 34816);    // [128][72]

  int br = blockIdx.y;
  const short* W1 = br ? w3f : w1f;
  const float* S1 = br ? s3 : s1;
  const float* B1 = br ? b3 : b1;
  const short* W2 = br ? w4f : w2f;
  const float* S2 = br ? s4 : s2;
  const float* B2 = br ? b4 : b2;
  const short* WA = br ? wa2f : wa1f;
  int KR = br ? 12 : 16;
  int FOFF = br ? 256 : 0;

  int tid = threadIdx.x;
  int lane = tid & 63;
  int w = tid >> 6;
  int lr = lane & 15;
  int lg = lane >> 4;
  int pbase = blockIdx.x * 8;
  const float* hb = h + ((size_t)(pbase & ~(NN - 1))) * 8;

  // Phase A: edge features (rows = point*16 + nbr), packed bf16 pair converts, b128 stores
  if (tid < 128) {
    int t = tid >> 4, j = tid & 15;
    int p = pbase + t;
    const float* cp = h + (size_t)p * 8;
    bool real = (j < KR);
    unsigned d0 = 0, d1 = 0, d2 = 0, d3 = 0, c0 = 0, c1 = 0, c2 = 0, c3 = 0;
    if (real) {
      int id = knn_idx[(size_t)p * 16 + j];
      const float* np_ = hb + (size_t)id * 8;
      float cv0 = cp[0], cv1 = cp[1], cv2 = cp[2], cv3 = cp[3];
      float cv4 = cp[4], cv5 = cp[5], cv6 = cp[6], cv7 = cp[7];
      d0 = f2bf2(np_[0] - cv0, np_[1] - cv1);
      d1 = f2bf2(np_[2] - cv2, np_[3] - cv3);
      d2 = f2bf2(np_[4] - cv4, np_[5] - cv5);
      d3 = f2bf2(np_[6] - cv6, np_[7] - cv7);
      c0 = f2bf2(cv0, cv1); c1 = f2bf2(cv2, cv3);
      c2 = f2bf2(cv4, cv5); c3 = f2bf2(cv6, cv7);
    }
    *(uint4*)&e_s[tid][0] = make_uint4(d0, d1, d2, d3);
    *(uint4*)&e_s[tid][8] = make_uint4(c0, c1, c2, c3);
    *(uint4*)&e_s[tid][16] = make_uint4(0, 0, 0, 0);
    *(uint4*)&e_s[tid][24] = make_uint4(0, 0, 0, 0);
  }
  __syncthreads();

  // Phase B: conv1 16->64. wave w: col-tile w&3, row-half w>>2.
  {
    int ct = w & 3;
    int rhalf = w >> 2;
    int o = ct * 16 + lr;
    bf16x8 bfrag = ((const bf16x8*)W1)[ct * 64 + lane];
    float scl = S1[o], bia = B1[o];
#pragma unroll
    for (int rt = 0; rt < 4; ++rt) {
      int rr = rhalf * 4 + rt;
      bf16x8 af = *(const bf16x8*)&e_s[rr * 16 + lr][lg * 8];
      f32x4 acc = {0.f, 0.f, 0.f, 0.f};
      acc = MFMA(af, bfrag, acc);
#pragma unroll
      for (int q = 0; q < 4; ++q) {
        g1_s[rr * 16 + lg * 4 + q][o] = f2bf_hw(fmaxf(acc[q] * scl + bia, 0.f));
      }
    }
  }
  __syncthreads();  // e_s dead from here; its bytes become g2_s

  // Phase C: conv2 64->128. wave w: col-tile w; fp32 copies kept in regs for pooling.
  float g2r[8][4];
  {
    int ct = w;
    int o = ct * 16 + lr;
    bf16x8 bf0 = ((const bf16x8*)W2)[(0 * 8 + ct) * 64 + lane];
    bf16x8 bf1 = ((const bf16x8*)W2)[(1 * 8 + ct) * 64 + lane];
    float scl = S2[o], bia = B2[o];
#pragma unroll
    for (int rt = 0; rt < 8; ++rt) {
      bf16x8 a0 = *(const bf16x8*)&g1_s[rt * 16 + lr][lg * 8];
      bf16x8 a1 = *(const bf16x8*)&g1_s[rt * 16 + lr][32 + lg * 8];
      f32x4 acc = {0.f, 0.f, 0.f, 0.f};
      acc = MFMA(a0, bf0, acc);
      acc = MFMA(a1, bf1, acc);
#pragma unroll
      for (int q = 0; q < 4; ++q) {
        float v = fmaxf(acc[q] * scl + bia, 0.f);
        g2r[rt][q] = v;
        g2_s[rt * 16 + lg * 4 + q][o] = f2bf_hw(v);
      }
    }
  }
  __syncthreads();

  // Phase D: att score (sigmoid)*g2, masked k-sum -> pooled into fbuf[p][FOFF..FOFF+128)
  {
    int ct = w;
    int o = ct * 16 + lr;
    bf16x8 bfr[4];
#pragma unroll
    for (int kt = 0; kt < 4; ++kt) bfr[kt] = ((const bf16x8*)WA)[(kt * 8 + ct) * 64 + lane];
#pragma unroll
    for (int rt = 0; rt < 8; ++rt) {
      f32x4 acc = {0.f, 0.f, 0.f, 0.f};
#pragma unroll
      for (int kt = 0; kt < 4; ++kt) {
        bf16x8 a = *(const bf16x8*)&g2_s[rt * 16 + lr][kt * 32 + lg * 8];
        acc = MFMA(a, bfr[kt], acc);
      }
      float v = 0.f;
#pragma unroll
      for (int q = 0; q < 4; ++q) {
        int jj = lg * 4 + q;
        float sg = __builtin_amdgcn_rcpf(1.f + __expf(-acc[q]));
        if (jj < KR) v += g2r[rt][q] * sg;
      }
      v += __shfl_xor(v, 16);
      v += __shfl_xor(v, 32);
      if (lane < 16)
        fout[(size_t)(pbase + rt) * 512 + FOFF + o] = f2bf_hw(v);
    }
  }
}

// ---------------- K3b: att conv 128->256 per branch, IN-PLACE on fbuf ----------------
__global__ __launch_bounds__(256, 4) void k_att(
    short* __restrict__ fb,
    const short* __restrict__ wp1f, const float* __restrict__ a1s, const float* __restrict__ a1b,
    const short* __restrict__ wp2f, const float* __restrict__ a2s, const float* __restrict__ a2b) {
  __shared__ short ptile[64][136];
  int br = blockIdx.y;
  const short* WP = br ? wp2f : wp1f;
  const float* SP = br ? a2s : a1s;
  const float* BP = br ? a2b : a1b;
  int FOFF = br ? 256 : 0;

  int tid = threadIdx.x;
  int lane = tid & 63;
  int w = tid >> 6;
  int lr = lane & 15;
  int lg = lane >> 4;
  int p0 = blockIdx.x * 64;

#pragma unroll
  for (int i = 0; i < 4; ++i) {
    int f = i * 256 + tid;
    int row = f >> 4, seg = f & 15;
    *(float4*)&ptile[row][seg * 8] =
        *(const float4*)(fb + (size_t)(p0 + row) * 512 + FOFF + seg * 8);
  }
  __syncthreads();

  bf16x8 af[4][4];
#pragma unroll
  for (int rt = 0; rt < 4; ++rt)
#pragma unroll
    for (int kt = 0; kt < 4; ++kt)
      af[rt][kt] = *(const bf16x8*)&ptile[rt * 16 + lr][kt * 32 + lg * 8];

#pragma unroll
  for (int cc = 0; cc < 4; ++cc) {
    int ct = w * 4 + cc;
    int o = ct * 16 + lr;
    bf16x8 bfr[4];
#pragma unroll
    for (int kt = 0; kt < 4; ++kt) bfr[kt] = ((const bf16x8*)WP)[(kt * 16 + ct) * 64 + lane];
    float scl = SP[o], bia = BP[o];
#pragma unroll
    for (int rt = 0; rt < 4; ++rt) {
      f32x4 acc = {0.f, 0.f, 0.f, 0.f};
#pragma unroll
      for (int kt = 0; kt < 4; ++kt) acc = MFMA(af[rt][kt], bfr[kt], acc);
#pragma unroll
      for (int q = 0; q < 4; ++q) {
        float v = fmaxf(acc[q] * scl + bia, 0.f);
        fb[(size_t)(p0 + rt * 16 + lg * 4 + q) * 512 + FOFF + o] = f2bf_hw(v);
      }
    }
  }
}

// ---------------- K4: out = relu(bn(f @ wf^T)) computed transposed ----------------
__global__ __launch_bounds__(256, 4) void k_final(
    const short* __restrict__ fbuf, const short* __restrict__ wff,
    const float* __restrict__ sf, const float* __restrict__ bfv,
    float* __restrict__ out) {
  __shared__ short b_s[256][72];
  int tid = threadIdx.x;
  int lane = tid & 63;
  int w = tid >> 6;
  int lr = lane & 15;
  int lg = lane >> 4;
  int ob = blockIdx.x;
  int p0 = blockIdx.y * 256;
  int rtg = ob * 4 + w;

  f32x4 acc[16];
#pragma unroll
  for (int ct = 0; ct < 16; ++ct) acc[ct] = (f32x4){0.f, 0.f, 0.f, 0.f};

  for (int kc = 0; kc < 512; kc += 64) {
    __syncthreads();
#pragma unroll
    for (int c = 0; c < 8; ++c) {
      int idx = c * 256 + tid;
      int row = idx >> 3, seg = idx & 7;
      *(float4*)&b_s[row][seg * 8] =
          *(const float4*)(fbuf + ((size_t)(p0 + row) * 512 + kc + seg * 8));
    }
    __syncthreads();
    int kt = kc >> 5;
    bf16x8 a0 = ((const bf16x8*)wff)[((size_t)(kt + 0) * 32 + rtg) * 64 + lane];
    bf16x8 a1 = ((const bf16x8*)wff)[((size_t)(kt + 1) * 32 + rtg) * 64 + lane];
#pragma unroll
    for (int ct = 0; ct < 16; ++ct) {
      bf16x8 bb0 = *(const bf16x8*)&b_s[ct * 16 + lr][lg * 8];
      bf16x8 bb1 = *(const bf16x8*)&b_s[ct * 16 + lr][32 + lg * 8];
      acc[ct] = MFMA(a0, bb0, acc[ct]);
      acc[ct] = MFMA(a1, bb1, acc[ct]);
    }
  }

  int b = p0 >> 11;
  int nb = p0 & (NN - 1);
#pragma unroll
  for (int q = 0; q < 4; ++q) {
    int o = rtg * 16 + lg * 4 + q;
    float scl = sf[o], bia = bfv[o];
#pragma unroll
    for (int ct = 0; ct < 16; ++ct) {
      int n = nb + ct * 16 + lr;
      float v = fmaxf(acc[ct][q] * scl + bia, 0.f);
      out[((size_t)b * 512 + o) * NN + n] = v;
    }
  }
}

extern "C" void kernel_launch(void* const* d_in, const int* in_sizes, int n_in,
                              void* d_out, int out_size, void* d_ws, size_t ws_size,
                              hipStream_t stream) {
  const float* x      = (const float*)d_in[0];
  const float* lw     = (const float*)d_in[1];
  const float* ls     = (const float*)d_in[2];
  const float* lb     = (const float*)d_in[3];
  const float* w1     = (const float*)d_in[4];
  const float* s1     = (const float*)d_in[5];
  const float* b1     = (const float*)d_in[6];
  const float* w2     = (const float*)d_in[7];
  const float* s2     = (const float*)d_in[8];
  const float* b2     = (const float*)d_in[9];
  const float* w3     = (const float*)d_in[10];
  const float* s3     = (const float*)d_in[11];
  const float* b3     = (const float*)d_in[12];
  const float* w4     = (const float*)d_in[13];
  const float* s4     = (const float*)d_in[14];
  const float* b4     = (const float*)d_in[15];
  const float* a1_att = (const float*)d_in[16];
  const float* a1_w   = (const float*)d_in[17];
  const float* a1_s   = (const float*)d_in[18];
  const float* a1_b   = (const float*)d_in[19];
  const float* a2_att = (const float*)d_in[20];
  const float* a2_w   = (const float*)d_in[21];
  const float* a2_s   = (const float*)d_in[22];
  const float* a2_b   = (const float*)d_in[23];
  const float* wf     = (const float*)d_in[24];
  const float* sf     = (const float*)d_in[25];
  const float* bf     = (const float*)d_in[26];
  float* out = (float*)d_out;

  char* ws = (char*)d_ws;
  float* h   = (float*)ws;                          ws += (size_t)BB * NN * 8 * 4;
  float* xx  = (float*)ws;                          ws += (size_t)BB * NN * 4;
  int* knn_idx = (int*)ws;                          ws += (size_t)BB * NN * 16 * 4;
  short* fbuf  = (short*)ws;                        ws += (size_t)BB * NN * 512 * 2;
  short* w1f   = (short*)ws;                        ws += 1 * 4 * 64 * 8 * 2;
  short* w3f   = (short*)ws;                        ws += 1 * 4 * 64 * 8 * 2;
  short* w2f   = (short*)ws;                        ws += 2 * 8 * 64 * 8 * 2;
  short* w4f   = (short*)ws;                        ws += 2 * 8 * 64 * 8 * 2;
  short* wa1f  = (short*)ws;                        ws += 4 * 8 * 64 * 8 * 2;
  short* wa2f  = (short*)ws;                        ws += 4 * 8 * 64 * 8 * 2;
  short* wp1f  = (short*)ws;                        ws += 4 * 16 * 64 * 8 * 2;
  short* wp2f  = (short*)ws;                        ws += 4 * 16 * 64 * 8 * 2;
  short* wff   = (short*)ws;                        ws += 16 * 32 * 64 * 8 * 2;

  k_packall<<<dim3(744), dim3(64), 0, stream>>>(
      w1, w3, w2, w4, a1_att, a2_att, a1_w, a2_w, wf,
      w1f, w3f, w2f, w4f, wa1f, wa2f, wp1f, wp2f, wff);

  k_h<<<dim3((BB * NN + 255) / 256), dim3(256), 0, stream>>>(x, lw, ls, lb, h, xx);
  k_knn<<<dim3(512), dim3(512), 0, stream>>>(h, xx, knn_idx);
  k_branch_all<<<dim3(BB * NN / 8, 2), dim3(512), 0, stream>>>(
      h, knn_idx,
      w1f, s1, b1, w2f, s2, b2, wa1f,
      w3f, s3, b3, w4f, s4, b4, wa2f, fbuf);
  k_att<<<dim3(BB * NN / 64, 2), dim3(256), 0, stream>>>(
      fbuf, wp1f, a1_s, a1_b, wp2f, a2_s, a2_b);
  k_final<<<dim3(8, 128), dim3(256), 0, stream>>>(fbuf, wff, sf, bf, out);
}

// Round 12
// 246.224 us; speedup vs baseline: 1.2569x; 1.0040x over previous
//
#include <hip/hip_runtime.h>
#include <hip/hip_bf16.h>
#include <math.h>

#define BB 16
#define NN 2048

typedef short bf16x8 __attribute__((ext_vector_type(8)));
typedef float f32x4 __attribute__((ext_vector_type(4)));
typedef unsigned long long u64;

#define MFMA(a, b, c) __builtin_amdgcn_mfma_f32_16x16x32_bf16(a, b, c, 0, 0, 0)

static __device__ __forceinline__ short f2bf(float f) {
  union { float f; unsigned u; } v; v.f = f;
  unsigned r = v.u + 0x7fffu + ((v.u >> 16) & 1u);
  return (short)(r >> 16);
}
static __device__ __forceinline__ short f2bf_hw(float f) {
  unsigned u;
  asm("v_cvt_pk_bf16_f32 %0, %1, %1" : "=v"(u) : "v"(f));
  return (short)u;
}
static __device__ __forceinline__ unsigned f2bf2(float lo, float hi) {
  unsigned u;
  asm("v_cvt_pk_bf16_f32 %0, %1, %2" : "=v"(u) : "v"(lo), "v"(hi));
  return u;
}

// ---------------- K1: h = relu(bn(conv1d(x))) ; xx = ||h||^2 ----------------
__global__ __launch_bounds__(256) void k_h(const float* __restrict__ x,
                                           const float* __restrict__ lw,
                                           const float* __restrict__ ls,
                                           const float* __restrict__ lb,
                                           float* __restrict__ h,
                                           float* __restrict__ xx) {
  int p = blockIdx.x * blockDim.x + threadIdx.x;
  if (p >= BB * NN) return;
  int b = p >> 11;
  int n = p & (NN - 1);
  const float* xb = x + (size_t)b * 3 * NN + n;
  float x0 = xb[0], x1 = xb[NN], x2 = xb[2 * NN];
  float hv[8];
  float ss = 0.f;
#pragma unroll
  for (int o = 0; o < 8; ++o) {
    float v = x0 * lw[o * 3 + 0] + x1 * lw[o * 3 + 1] + x2 * lw[o * 3 + 2];
    v = fmaxf(v * ls[o] + lb[o], 0.f);
    hv[o] = v;
    ss += v * v;  // same order as k_knn inner product -> self-dist exactly 0
  }
  float4* hp = (float4*)(h + (size_t)p * 8);
  hp[0] = make_float4(hv[0], hv[1], hv[2], hv[3]);
  hp[1] = make_float4(hv[4], hv[5], hv[6], hv[7]);
  xx[p] = ss;
}

// ---------------- K2: kNN top-16 (r8/r9 version, proven) ----------------
__global__ __launch_bounds__(512, 4) void k_knn(const float* __restrict__ h,
                                                const float* __restrict__ xx,
                                                int* __restrict__ knn_idx) {
  __shared__ __align__(16) unsigned char smem[52224];
  float4* sh4 = (float4*)smem;
  float* sxx = (float*)(smem + 16384);
  unsigned* thr = (unsigned*)(smem + 18432);
  u64* stkb = (u64*)(smem + 18688);

  int tid = threadIdx.x;
  int lane = tid & 63;
  int w = tid >> 6;
  int blk = blockIdx.x;
  int b = blk >> 5;
  int qloc = ((blk & 31) << 6) + lane;
  int p = (b << 11) + qloc;
  const float* hb = h + ((size_t)b << 11) * 8;
  const float* xxb = xx + ((size_t)b << 11);

  const float4* qp = (const float4*)(hb + (size_t)qloc * 8);
  float4 q0 = qp[0], q1 = qp[1];
  float xq = xxb[qloc];

  if (tid < 64) thr[tid] = 0x007FFFFFu;
  __syncthreads();

  u64* stkrow = stkb + tid * 8;
  u64 a[16];
#pragma unroll
  for (int i = 0; i < 16; ++i) a[i] = 0ULL;
  int cnt = 0;

  auto inner8 = [&](int s) -> float {
    float4 a0 = sh4[(w * 64 + s) * 2 + 0];
    float4 a1 = sh4[(w * 64 + s) * 2 + 1];
    return q0.x * a0.x + q0.y * a0.y + q0.z * a0.z + q0.w * a0.w +
           q1.x * a1.x + q1.y * a1.y + q1.z * a1.z + q1.w * a1.w;
  };
  auto mkkey = [&](float d, int mg) -> u64 {
    unsigned uu = __float_as_uint(d);
    unsigned key = ((int)uu >= 0) ? (uu | 0x80000000u) : ~uu;
    return ((u64)key << 32) | (unsigned)(NN - 1 - mg);
  };

  auto flush = [&]() {
    u64 c[8];
#pragma unroll
    for (int j = 0; j < 8; ++j) {
      u64 v = stkrow[j];
      c[j] = (j < cnt) ? v : 0ULL;
    }
    cnt = 0;
#pragma unroll
    for (int k = 2; k <= 8; k <<= 1)
#pragma unroll
      for (int j = k >> 1; j > 0; j >>= 1)
#pragma unroll
        for (int i = 0; i < 8; ++i) {
          int l = i ^ j;
          if (l > i) {
            bool up = ((i & k) == 0);
            u64 xi = c[i], xl = c[l];
            bool sw = up ? (xi > xl) : (xi < xl);
            if (sw) { c[i] = xl; c[l] = xi; }
          }
        }
    u64 m[16];
#pragma unroll
    for (int i = 0; i < 16; ++i) {
      u64 bi = (i < 8) ? c[7 - i] : 0ULL;
      m[i] = (a[i] > bi) ? a[i] : bi;
    }
#pragma unroll
    for (int j = 8; j > 0; j >>= 1)
#pragma unroll
      for (int i = 0; i < 16; ++i) {
        int l = i ^ j;
        if (l > i && m[i] > m[l]) { u64 t = m[i]; m[i] = m[l]; m[l] = t; }
      }
#pragma unroll
    for (int i = 0; i < 16; ++i) a[i] = m[i];
  };

  int sbase = w * 256;
  float4 r0, r1;
  float rx;
  {
    const float* cp = hb + (size_t)(sbase + lane) * 8;
    r0 = *(const float4*)cp;
    r1 = *(const float4*)(cp + 4);
    rx = xxb[sbase + lane];
  }
  for (int c2 = 0; c2 < 4; ++c2) {
    sh4[(w * 64 + lane) * 2 + 0] = r0;
    sh4[(w * 64 + lane) * 2 + 1] = r1;
    sxx[w * 64 + lane] = rx;
    if (c2 < 3) {
      const float* cp = hb + (size_t)(sbase + (c2 + 1) * 64 + lane) * 8;
      r0 = *(const float4*)cp;
      r1 = *(const float4*)(cp + 4);
      rx = xxb[sbase + (c2 + 1) * 64 + lane];
    }
    int mg0 = sbase + c2 * 64;
    int sstart = 0;
    if (c2 == 0) {
      u64 cc[16];
#pragma unroll
      for (int j = 0; j < 16; ++j) cc[j] = mkkey(2.f * inner8(j) - xq - sxx[w * 64 + j], mg0 + j);
#pragma unroll
      for (int k = 2; k <= 16; k <<= 1)
#pragma unroll
        for (int j = k >> 1; j > 0; j >>= 1)
#pragma unroll
          for (int i = 0; i < 16; ++i) {
            int l = i ^ j;
            if (l > i) {
              bool up = ((i & k) == 0);
              u64 xi = cc[i], xl = cc[l];
              bool sw = up ? (xi > xl) : (xi < xl);
              if (sw) { cc[i] = xl; cc[l] = xi; }
            }
          }
#pragma unroll
      for (int i = 0; i < 16; ++i) a[i] = cc[i];
      atomicMax(&thr[lane], (unsigned)(a[0] >> 32));
      sstart = 16;
    }
    for (int s16 = sstart; s16 < 64; s16 += 16) {
      unsigned t32 = thr[lane];
      unsigned tu = (t32 & 0x80000000u) ? (t32 & 0x7fffffffu) : ~t32;
      float thrF = __uint_as_float(tu);
#pragma unroll
      for (int s4 = 0; s4 < 16; s4 += 4) {
        int s = s16 + s4;
        float4 xm4 = *(const float4*)&sxx[w * 64 + s];
#pragma unroll
        for (int u = 0; u < 4; ++u) {
          float xm = (u == 0) ? xm4.x : (u == 1) ? xm4.y : (u == 2) ? xm4.z : xm4.w;
          float d = 2.f * inner8(s + u) - xq - xm;
          if (d >= thrF) { stkrow[cnt] = mkkey(d, mg0 + s + u); cnt++; }
        }
        if (__any(cnt >= 5)) {
          flush();
          atomicMax(&thr[lane], (unsigned)(a[0] >> 32));
          unsigned t2 = thr[lane];
          unsigned tu2 = (t2 & 0x80000000u) ? (t2 & 0x7fffffffu) : ~t2;
          thrF = __uint_as_float(tu2);
        }
      }
    }
  }
  if (__any(cnt > 0)) flush();

  u64* M1 = (u64*)smem;
  u64* M2 = (u64*)(smem + 34816);
  u64* M3 = (u64*)smem;

  auto mergeLds = [&](const u64* src) {
    u64 m[16];
#pragma unroll
    for (int i = 0; i < 16; ++i) {
      u64 bi = src[15 - i];
      m[i] = (a[i] > bi) ? a[i] : bi;
    }
#pragma unroll
    for (int j = 8; j > 0; j >>= 1)
#pragma unroll
      for (int i = 0; i < 16; ++i) {
        int l = i ^ j;
        if (l > i && m[i] > m[l]) { u64 t = m[i]; m[i] = m[l]; m[l] = t; }
      }
#pragma unroll
    for (int i = 0; i < 16; ++i) a[i] = m[i];
  };

  __syncthreads();
  if (w >= 4) {
#pragma unroll
    for (int i = 0; i < 16; ++i) M1[((w - 4) * 64 + lane) * 17 + i] = a[i];
  }
  __syncthreads();
  if (w < 4) mergeLds(&M1[(w * 64 + lane) * 17]);
  __syncthreads();
  if (w == 2 || w == 3) {
#pragma unroll
    for (int i = 0; i < 16; ++i) M2[((w - 2) * 64 + lane) * 17 + i] = a[i];
  }
  __syncthreads();
  if (w < 2) mergeLds(&M2[(w * 64 + lane) * 17]);
  __syncthreads();
  if (w == 1) {
#pragma unroll
    for (int i = 0; i < 16; ++i) M3[lane * 17 + i] = a[i];
  }
  __syncthreads();
  if (w == 0) {
    mergeLds(&M3[lane * 17]);
    int ids[16];
#pragma unroll
    for (int r = 0; r < 16; ++r)
      ids[r] = (NN - 1) - (int)(unsigned)(a[15 - r] & 0xFFFFFFFFULL);
    int4* op = (int4*)(knn_idx + (size_t)p * 16);
    op[0] = make_int4(ids[0], ids[1], ids[2], ids[3]);
    op[1] = make_int4(ids[4], ids[5], ids[6], ids[7]);
    op[2] = make_int4(ids[8], ids[9], ids[10], ids[11]);
    op[3] = make_int4(ids[12], ids[13], ids[14], ids[15]);
  }
}

// ---------------- unified weight pack ----------------
__global__ __launch_bounds__(64) void k_packall(
    const float* __restrict__ w1, const float* __restrict__ w3,
    const float* __restrict__ w2, const float* __restrict__ w4,
    const float* __restrict__ a1_att, const float* __restrict__ a2_att,
    const float* __restrict__ a1_w, const float* __restrict__ a2_w,
    const float* __restrict__ wf,
    short* __restrict__ w1f, short* __restrict__ w3f,
    short* __restrict__ w2f, short* __restrict__ w4f,
    short* __restrict__ wa1f, short* __restrict__ wa2f,
    short* __restrict__ wp1f, short* __restrict__ wp2f,
    short* __restrict__ wff) {
  int bb = blockIdx.x;
  const float* src;
  short* dst;
  int O, C, base;
  if (bb < 4)        { src = w1;     dst = w1f;  O = 64;  C = 16;  base = 0; }
  else if (bb < 8)   { src = w3;     dst = w3f;  O = 64;  C = 16;  base = 4; }
  else if (bb < 24)  { src = w2;     dst = w2f;  O = 128; C = 64;  base = 8; }
  else if (bb < 40)  { src = w4;     dst = w4f;  O = 128; C = 64;  base = 24; }
  else if (bb < 72)  { src = a1_att; dst = wa1f; O = 128; C = 128; base = 40; }
  else if (bb < 104) { src = a2_att; dst = wa2f; O = 128; C = 128; base = 72; }
  else if (bb < 168) { src = a1_w;   dst = wp1f; O = 256; C = 128; base = 104; }
  else if (bb < 232) { src = a2_w;   dst = wp2f; O = 256; C = 128; base = 168; }
  else               { src = wf;     dst = wff;  O = 512; C = 512; base = 232; }
  int blk = bb - base;
  int NCT = O >> 4;
  int ct = blk % NCT;
  int kt = blk / NCT;
  int l = threadIdx.x;
  int col = ct * 16 + (l & 15);
  bf16x8 v;
#pragma unroll
  for (int i = 0; i < 8; ++i) {
    int k = kt * 32 + ((l >> 4) << 3) + i;
    v[i] = (k < C) ? f2bf(src[(size_t)col * C + k]) : (short)0;
  }
  ((bf16x8*)dst)[(size_t)blk * 64 + l] = v;
}

// ---------------- K3: edge->conv1->conv2->att-score->pool ----------------
// r11 body + T2 XOR-swizzle on g1_s/g2_s columns: col ^= ((row>>2)&7)<<3 (shorts).
// Key is 16B-granular (b128 chunks stay contiguous), <128B (bijective within row),
// contains both lg bits -> per-wave epilogue writes spread over all 32 banks (2/bank).
__global__ __launch_bounds__(512, 6) void k_branch_all(
    const float* __restrict__ h, const int* __restrict__ knn_idx,
    const short* __restrict__ w1f, const float* __restrict__ s1, const float* __restrict__ b1,
    const short* __restrict__ w2f, const float* __restrict__ s2, const float* __restrict__ b2,
    const short* __restrict__ wa1f,
    const short* __restrict__ w3f, const float* __restrict__ s3, const float* __restrict__ b3,
    const short* __restrict__ w4f, const float* __restrict__ s4, const float* __restrict__ b4,
    const short* __restrict__ wa2f,
    short* __restrict__ fout) {
  __shared__ __align__(16) unsigned char smem[53248];
  short (*e_s)[40]  = (short(*)[40])smem;              // [128][40], phases A-B only
  short (*g2_s)[136] = (short(*)[136])smem;            // [128][136], phases C-D (overlays e_s)
  short (*g1_s)[72] = (short(*)[72])(smem + 34816);    // [128][72]

  auto swz = [](int r, int c) -> int { return c ^ (((r >> 2) & 7) << 3); };

  int br = blockIdx.y;
  const short* W1 = br ? w3f : w1f;
  const float* S1 = br ? s3 : s1;
  const float* B1 = br ? b3 : b1;
  const short* W2 = br ? w4f : w2f;
  const float* S2 = br ? s4 : s2;
  const float* B2 = br ? b4 : b2;
  const short* WA = br ? wa2f : wa1f;
  int KR = br ? 12 : 16;
  int FOFF = br ? 256 : 0;

  int tid = threadIdx.x;
  int lane = tid & 63;
  int w = tid >> 6;
  int lr = lane & 15;
  int lg = lane >> 4;
  int pbase = blockIdx.x * 8;
  const float* hb = h + ((size_t)(pbase & ~(NN - 1))) * 8;

  // Phase A: edge features (rows = point*16 + nbr), packed bf16 pair converts, b128 stores
  if (tid < 128) {
    int t = tid >> 4, j = tid & 15;
    int p = pbase + t;
    const float* cp = h + (size_t)p * 8;
    bool real = (j < KR);
    unsigned d0 = 0, d1 = 0, d2 = 0, d3 = 0, c0 = 0, c1 = 0, c2 = 0, c3 = 0;
    if (real) {
      int id = knn_idx[(size_t)p * 16 + j];
      const float* np_ = hb + (size_t)id * 8;
      float cv0 = cp[0], cv1 = cp[1], cv2 = cp[2], cv3 = cp[3];
      float cv4 = cp[4], cv5 = cp[5], cv6 = cp[6], cv7 = cp[7];
      d0 = f2bf2(np_[0] - cv0, np_[1] - cv1);
      d1 = f2bf2(np_[2] - cv2, np_[3] - cv3);
      d2 = f2bf2(np_[4] - cv4, np_[5] - cv5);
      d3 = f2bf2(np_[6] - cv6, np_[7] - cv7);
      c0 = f2bf2(cv0, cv1); c1 = f2bf2(cv2, cv3);
      c2 = f2bf2(cv4, cv5); c3 = f2bf2(cv6, cv7);
    }
    *(uint4*)&e_s[tid][0] = make_uint4(d0, d1, d2, d3);
    *(uint4*)&e_s[tid][8] = make_uint4(c0, c1, c2, c3);
    *(uint4*)&e_s[tid][16] = make_uint4(0, 0, 0, 0);
    *(uint4*)&e_s[tid][24] = make_uint4(0, 0, 0, 0);
  }
  __syncthreads();

  // Phase B: conv1 16->64. wave w: col-tile w&3, row-half w>>2. Swizzled g1 writes.
  {
    int ct = w & 3;
    int rhalf = w >> 2;
    int o = ct * 16 + lr;
    bf16x8 bfrag = ((const bf16x8*)W1)[ct * 64 + lane];
    float scl = S1[o], bia = B1[o];
#pragma unroll
    for (int rt = 0; rt < 4; ++rt) {
      int rr = rhalf * 4 + rt;
      bf16x8 af = *(const bf16x8*)&e_s[rr * 16 + lr][lg * 8];
      f32x4 acc = {0.f, 0.f, 0.f, 0.f};
      acc = MFMA(af, bfrag, acc);
#pragma unroll
      for (int q = 0; q < 4; ++q) {
        int rw = rr * 16 + lg * 4 + q;
        g1_s[rw][swz(rw, o)] = f2bf_hw(fmaxf(acc[q] * scl + bia, 0.f));
      }
    }
  }
  __syncthreads();  // e_s dead from here; its bytes become g2_s

  // Phase C: conv2 64->128. Swizzled g1 reads, swizzled g2 writes; fp32 copies in regs.
  float g2r[8][4];
  {
    int ct = w;
    int o = ct * 16 + lr;
    bf16x8 bf0 = ((const bf16x8*)W2)[(0 * 8 + ct) * 64 + lane];
    bf16x8 bf1 = ((const bf16x8*)W2)[(1 * 8 + ct) * 64 + lane];
    float scl = S2[o], bia = B2[o];
#pragma unroll
    for (int rt = 0; rt < 8; ++rt) {
      int rr = rt * 16 + lr;
      bf16x8 a0 = *(const bf16x8*)&g1_s[rr][swz(rr, lg * 8)];
      bf16x8 a1 = *(const bf16x8*)&g1_s[rr][swz(rr, 32 + lg * 8)];
      f32x4 acc = {0.f, 0.f, 0.f, 0.f};
      acc = MFMA(a0, bf0, acc);
      acc = MFMA(a1, bf1, acc);
#pragma unroll
      for (int q = 0; q < 4; ++q) {
        float v = fmaxf(acc[q] * scl + bia, 0.f);
        g2r[rt][q] = v;
        int rw = rt * 16 + lg * 4 + q;
        g2_s[rw][swz(rw, o)] = f2bf_hw(v);
      }
    }
  }
  __syncthreads();

  // Phase D: att score (sigmoid)*g2 (swizzled reads), masked k-sum -> fbuf[p][FOFF..FOFF+128)
  {
    int ct = w;
    int o = ct * 16 + lr;
    bf16x8 bfr[4];
#pragma unroll
    for (int kt = 0; kt < 4; ++kt) bfr[kt] = ((const bf16x8*)WA)[(kt * 8 + ct) * 64 + lane];
#pragma unroll
    for (int rt = 0; rt < 8; ++rt) {
      int rr = rt * 16 + lr;
      f32x4 acc = {0.f, 0.f, 0.f, 0.f};
#pragma unroll
      for (int kt = 0; kt < 4; ++kt) {
        bf16x8 a = *(const bf16x8*)&g2_s[rr][swz(rr, kt * 32 + lg * 8)];
        acc = MFMA(a, bfr[kt], acc);
      }
      float v = 0.f;
#pragma unroll
      for (int q = 0; q < 4; ++q) {
        int jj = lg * 4 + q;
        float sg = __builtin_amdgcn_rcpf(1.f + __expf(-acc[q]));
        if (jj < KR) v += g2r[rt][q] * sg;
      }
      v += __shfl_xor(v, 16);
      v += __shfl_xor(v, 32);
      if (lane < 16)
        fout[(size_t)(pbase + rt) * 512 + FOFF + o] = f2bf_hw(v);
    }
  }
}

// ---------------- K3b: att conv 128->256 per branch, IN-PLACE on fbuf ----------------
__global__ __launch_bounds__(256, 4) void k_att(
    short* __restrict__ fb,
    const short* __restrict__ wp1f, const float* __restrict__ a1s, const float* __restrict__ a1b,
    const short* __restrict__ wp2f, const float* __restrict__ a2s, const float* __restrict__ a2b) {
  __shared__ short ptile[64][136];
  int br = blockIdx.y;
  const short* WP = br ? wp2f : wp1f;
  const float* SP = br ? a2s : a1s;
  const float* BP = br ? a2b : a1b;
  int FOFF = br ? 256 : 0;

  int tid = threadIdx.x;
  int lane = tid & 63;
  int w = tid >> 6;
  int lr = lane & 15;
  int lg = lane >> 4;
  int p0 = blockIdx.x * 64;

#pragma unroll
  for (int i = 0; i < 4; ++i) {
    int f = i * 256 + tid;
    int row = f >> 4, seg = f & 15;
    *(float4*)&ptile[row][seg * 8] =
        *(const float4*)(fb + (size_t)(p0 + row) * 512 + FOFF + seg * 8);
  }
  __syncthreads();

  bf16x8 af[4][4];
#pragma unroll
  for (int rt = 0; rt < 4; ++rt)
#pragma unroll
    for (int kt = 0; kt < 4; ++kt)
      af[rt][kt] = *(const bf16x8*)&ptile[rt * 16 + lr][kt * 32 + lg * 8];

#pragma unroll
  for (int cc = 0; cc < 4; ++cc) {
    int ct = w * 4 + cc;
    int o = ct * 16 + lr;
    bf16x8 bfr[4];
#pragma unroll
    for (int kt = 0; kt < 4; ++kt) bfr[kt] = ((const bf16x8*)WP)[(kt * 16 + ct) * 64 + lane];
    float scl = SP[o], bia = BP[o];
#pragma unroll
    for (int rt = 0; rt < 4; ++rt) {
      f32x4 acc = {0.f, 0.f, 0.f, 0.f};
#pragma unroll
      for (int kt = 0; kt < 4; ++kt) acc = MFMA(af[rt][kt], bfr[kt], acc);
#pragma unroll
      for (int q = 0; q < 4; ++q) {
        float v = fmaxf(acc[q] * scl + bia, 0.f);
        fb[(size_t)(p0 + rt * 16 + lg * 4 + q) * 512 + FOFF + o] = f2bf_hw(v);
      }
    }
  }
}

// ---------------- K4: out = relu(bn(f @ wf^T)) computed transposed ----------------
__global__ __launch_bounds__(256, 4) void k_final(
    const short* __restrict__ fbuf, const short* __restrict__ wff,
    const float* __restrict__ sf, const float* __restrict__ bfv,
    float* __restrict__ out) {
  __shared__ short b_s[256][72];
  int tid = threadIdx.x;
  int lane = tid & 63;
  int w = tid >> 6;
  int lr = lane & 15;
  int lg = lane >> 4;
  int ob = blockIdx.x;
  int p0 = blockIdx.y * 256;
  int rtg = ob * 4 + w;

  f32x4 acc[16];
#pragma unroll
  for (int ct = 0; ct < 16; ++ct) acc[ct] = (f32x4){0.f, 0.f, 0.f, 0.f};

  for (int kc = 0; kc < 512; kc += 64) {
    __syncthreads();
#pragma unroll
    for (int c = 0; c < 8; ++c) {
      int idx = c * 256 + tid;
      int row = idx >> 3, seg = idx & 7;
      *(float4*)&b_s[row][seg * 8] =
          *(const float4*)(fbuf + ((size_t)(p0 + row) * 512 + kc + seg * 8));
    }
    __syncthreads();
    int kt = kc >> 5;
    bf16x8 a0 = ((const bf16x8*)wff)[((size_t)(kt + 0) * 32 + rtg) * 64 + lane];
    bf16x8 a1 = ((const bf16x8*)wff)[((size_t)(kt + 1) * 32 + rtg) * 64 + lane];
#pragma unroll
    for (int ct = 0; ct < 16; ++ct) {
      bf16x8 bb0 = *(const bf16x8*)&b_s[ct * 16 + lr][lg * 8];
      bf16x8 bb1 = *(const bf16x8*)&b_s[ct * 16 + lr][32 + lg * 8];
      acc[ct] = MFMA(a0, bb0, acc[ct]);
      acc[ct] = MFMA(a1, bb1, acc[ct]);
    }
  }

  int b = p0 >> 11;
  int nb = p0 & (NN - 1);
#pragma unroll
  for (int q = 0; q < 4; ++q) {
    int o = rtg * 16 + lg * 4 + q;
    float scl = sf[o], bia = bfv[o];
#pragma unroll
    for (int ct = 0; ct < 16; ++ct) {
      int n = nb + ct * 16 + lr;
      float v = fmaxf(acc[ct][q] * scl + bia, 0.f);
      out[((size_t)b * 512 + o) * NN + n] = v;
    }
  }
}

extern "C" void kernel_launch(void* const* d_in, const int* in_sizes, int n_in,
                              void* d_out, int out_size, void* d_ws, size_t ws_size,
                              hipStream_t stream) {
  const float* x      = (const float*)d_in[0];
  const float* lw     = (const float*)d_in[1];
  const float* ls     = (const float*)d_in[2];
  const float* lb     = (const float*)d_in[3];
  const float* w1     = (const float*)d_in[4];
  const float* s1     = (const float*)d_in[5];
  const float* b1     = (const float*)d_in[6];
  const float* w2     = (const float*)d_in[7];
  const float* s2     = (const float*)d_in[8];
  const float* b2     = (const float*)d_in[9];
  const float* w3     = (const float*)d_in[10];
  const float* s3     = (const float*)d_in[11];
  const float* b3     = (const float*)d_in[12];
  const float* w4     = (const float*)d_in[13];
  const float* s4     = (const float*)d_in[14];
  const float* b4     = (const float*)d_in[15];
  const float* a1_att = (const float*)d_in[16];
  const float* a1_w   = (const float*)d_in[17];
  const float* a1_s   = (const float*)d_in[18];
  const float* a1_b   = (const float*)d_in[19];
  const float* a2_att = (const float*)d_in[20];
  const float* a2_w   = (const float*)d_in[21];
  const float* a2_s   = (const float*)d_in[22];
  const float* a2_b   = (const float*)d_in[23];
  const float* wf     = (const float*)d_in[24];
  const float* sf     = (const float*)d_in[25];
  const float* bf     = (const float*)d_in[26];
  float* out = (float*)d_out;

  char* ws = (char*)d_ws;
  float* h   = (float*)ws;                          ws += (size_t)BB * NN * 8 * 4;
  float* xx  = (float*)ws;                          ws += (size_t)BB * NN * 4;
  int* knn_idx = (int*)ws;                          ws += (size_t)BB * NN * 16 * 4;
  short* fbuf  = (short*)ws;                        ws += (size_t)BB * NN * 512 * 2;
  short* w1f   = (short*)ws;                        ws += 1 * 4 * 64 * 8 * 2;
  short* w3f   = (short*)ws;                        ws += 1 * 4 * 64 * 8 * 2;
  short* w2f   = (short*)ws;                        ws += 2 * 8 * 64 * 8 * 2;
  short* w4f   = (short*)ws;                        ws += 2 * 8 * 64 * 8 * 2;
  short* wa1f  = (short*)ws;                        ws += 4 * 8 * 64 * 8 * 2;
  short* wa2f  = (short*)ws;                        ws += 4 * 8 * 64 * 8 * 2;
  short* wp1f  = (short*)ws;                        ws += 4 * 16 * 64 * 8 * 2;
  short* wp2f  = (short*)ws;                        ws += 4 * 16 * 64 * 8 * 2;
  short* wff   = (short*)ws;                        ws += 16 * 32 * 64 * 8 * 2;

  k_packall<<<dim3(744), dim3(64), 0, stream>>>(
      w1, w3, w2, w4, a1_att, a2_att, a1_w, a2_w, wf,
      w1f, w3f, w2f, w4f, wa1f, wa2f, wp1f, wp2f, wff);

  k_h<<<dim3((BB * NN + 255) / 256), dim3(256), 0, stream>>>(x, lw, ls, lb, h, xx);
  k_knn<<<dim3(512), dim3(512), 0, stream>>>(h, xx, knn_idx);
  k_branch_all<<<dim3(BB * NN / 8, 2), dim3(512), 0, stream>>>(
      h, knn_idx,
      w1f, s1, b1, w2f, s2, b2, wa1f,
      w3f, s3, b3, w4f, s4, b4, wa2f, fbuf);
  k_att<<<dim3(BB * NN / 64, 2), dim3(256), 0, stream>>>(
      fbuf, wp1f, a1_s, a1_b, wp2f, a2_s, a2_b);
  k_final<<<dim3(8, 128), dim3(256), 0, stream>>>(fbuf, wff, sf, bf, out);
}